// Round 10
// baseline (97.252 us; speedup 1.0000x reference)
//
#include <hip/hip_runtime.h>
#include <cstdint>
#include <cstddef>

#define BATCH 64
#define PRI   8732
#define NCLS  81
#define NEGPOS 3
#define NTOT  (BATCH * PRI)          // 558848
#define PPB   128                    // priors per window
#define NWIN  (NTOT / PPB)           // 4366 exactly
#define WFLOATS (PPB * NCLS)         // 10368 floats per window
#define WF4   (WFLOATS / 4)          // 2592 float4s per window
#define NBLKM 256                    // persistent blocks, 1/CU

__device__ __forceinline__ unsigned keymap(float f) {
    unsigned u = __float_as_uint(f);
    return (u & 0x80000000u) ? ~u : (u | 0x80000000u);
}

__device__ __forceinline__ void gl_lds16(const float4* g, float4* l) {
    __builtin_amdgcn_global_load_lds(
        (const __attribute__((address_space(1))) void*)(const void*)g,
        (__attribute__((address_space(3))) void*)(void*)l, 16, 0, 0);
}

struct Phase1 {
    float lds[2][WFLOATS];           // 82944 B
    int   labs[2][PPB];              // 1024 B
    float red0[16], red1[16];
};
struct Phase2 {
    unsigned keys[PRI];              // 34928 B
    unsigned hist[16][257];          // 16448 B
    unsigned ured[16];
    float    fred[16], fred2[16];
    unsigned sh_prefix, sh_r;
    int      sh_flag;
};

// ---------------------------------------------------------------------------
// ONE persistent kernel. 256 blocks x 1024 threads (1 block/CU, 84 KB LDS).
// Phase 1 (all blocks): R6-style dbuf global_load_lds stream over windows
//   w = bid + i*256 (128 priors, 41.5 KB); 8 lanes/prior softmax (R7-verified
//   masks), keymapped bg keys (positives -> 0), per-block ce/sl partials.
// Ticket 1 (device-scope fence + atomic, R8-proven pattern).
// Phase 2 (blocks 0..63, after spin): R6's k_row verbatim — wave-private
//   hist radix select over the row's keys, selected-negative sum.
// Ticket 2: last row-block reduces cepart/slpart/rowobj/rownp -> out.
// ---------------------------------------------------------------------------
__global__ __launch_bounds__(1024) void k_all(const float* __restrict__ conf,
                                              const int* __restrict__ labels,
                                              const float* __restrict__ ploc,
                                              const float* __restrict__ gloc,
                                              unsigned* __restrict__ keysg,
                                              float* __restrict__ cepart,
                                              float* __restrict__ slpart,
                                              unsigned* __restrict__ counter,
                                              float* __restrict__ rowobj,
                                              float* __restrict__ rownp,
                                              float* __restrict__ out) {
    __shared__ union { Phase1 p1; Phase2 p2; } sm;
    const int t = threadIdx.x;
    const int bid = blockIdx.x;
    const int wid = t >> 6, lane = t & 63;

    // ================= PHASE 1 =================
    {
        float ceacc = 0.0f, slacc = 0.0f;
        const float4* conf4 = reinterpret_cast<const float4*>(conf);

        auto stage = [&](int buf, int w) {
            const float4* g4 = conf4 + (size_t)w * WF4;
            float4* l4 = reinterpret_cast<float4*>(&sm.p1.lds[buf][0]);
            gl_lds16(&g4[t], &l4[t]);
            gl_lds16(&g4[t + 1024], &l4[t + 1024]);
            if (t < WF4 - 2048) gl_lds16(&g4[t + 2048], &l4[t + 2048]); // 544
            if (t < PPB) sm.p1.labs[buf][t] = labels[w * PPB + t];
        };

        stage(0, bid);
        __syncthreads();

        int cur = 0;
        for (int i = 0; ; ++i) {
            const int w  = bid + i * NBLKM;
            const int wn = w + NBLKM;
            const bool more = (wn < NWIN);
            if (more) stage(cur ^ 1, wn);

            // ---- compute window w: prior q = t>>3, eighth h = t&7
            const float* B = &sm.p1.lds[cur][0];
            const int q   = t >> 3, h = t & 7;
            const int f0  = q * NCLS + 10 * h;
            const int len = (h == 7) ? 11 : 10;
            const int a0  = f0 & ~3;
            const int o   = f0 & 3;
            const int ve  = o + len;              // 10..14

            const float4* lp = reinterpret_cast<const float4*>(B + a0);
            float4 v0 = lp[0], v1 = lp[1], v2 = lp[2], v3 = lp[3];
            v0.x = (o > 0) ? -INFINITY : v0.x;
            v0.y = (o > 1) ? -INFINITY : v0.y;
            v0.z = (o > 2) ? -INFINITY : v0.z;
            v2.z = (ve > 10) ? v2.z : -INFINITY;
            v2.w = (ve > 11) ? v2.w : -INFINITY;
            v3.x = (ve > 12) ? v3.x : -INFINITY;
            v3.y = (ve > 13) ? v3.y : -INFINITY;
            v3.z = -INFINITY;
            v3.w = -INFINITY;

            float m;
            {
                float a = fmaxf(fmaxf(v0.x, v0.y), fmaxf(v0.z, v0.w));
                float c = fmaxf(fmaxf(v1.x, v1.y), fmaxf(v1.z, v1.w));
                float d = fmaxf(fmaxf(v2.x, v2.y), fmaxf(v2.z, v2.w));
                float e = fmaxf(v3.x, v3.y);
                m = fmaxf(fmaxf(a, c), fmaxf(d, e));
            }
            float s =
                __expf(v0.x - m) + __expf(v0.y - m) + __expf(v0.z - m) + __expf(v0.w - m) +
                __expf(v1.x - m) + __expf(v1.y - m) + __expf(v1.z - m) + __expf(v1.w - m) +
                __expf(v2.x - m) + __expf(v2.y - m) + __expf(v2.z - m) + __expf(v2.w - m) +
                __expf(v3.x - m) + __expf(v3.y - m);

#pragma unroll
            for (int off = 1; off <= 4; off <<= 1) {
                const float mo = __shfl_xor(m, off, 64);
                const float so = __shfl_xor(s, off, 64);
                const float mn = fmaxf(m, mo);
                s = s * __expf(m - mn) + so * __expf(mo - mn);
                m = mn;
            }
            const float lse = m + __logf(s);

            if (h == 0) {
                const int p   = w * PPB + q;
                const int lab = sm.p1.labs[cur][q];
                const float c0 = B[q * NCLS];
                unsigned key = 0u;
                if (lab > 0) {
                    ceacc += lse - B[q * NCLS + lab];
                    const float4 pl = *reinterpret_cast<const float4*>(ploc + (size_t)p * 4);
                    const float4 gl = *reinterpret_cast<const float4*>(gloc + (size_t)p * 4);
                    float d, a;
                    d = pl.x - gl.x; a = fabsf(d); slacc += (a < 1.0f) ? 0.5f * d * d : a - 0.5f;
                    d = pl.y - gl.y; a = fabsf(d); slacc += (a < 1.0f) ? 0.5f * d * d : a - 0.5f;
                    d = pl.z - gl.z; a = fabsf(d); slacc += (a < 1.0f) ? 0.5f * d * d : a - 0.5f;
                    d = pl.w - gl.w; a = fabsf(d); slacc += (a < 1.0f) ? 0.5f * d * d : a - 0.5f;
                } else {
                    key = keymap(lse - c0);       // bg >= 0 -> key != 0
                }
                keysg[p] = key;
            }

            if (!more) break;
            __syncthreads();                      // DMA(wn) + readers drained
            cur ^= 1;
        }

        // block reduce partials
#pragma unroll
        for (int off = 32; off > 0; off >>= 1) {
            ceacc += __shfl_xor(ceacc, off, 64);
            slacc += __shfl_xor(slacc, off, 64);
        }
        __syncthreads();
        if (lane == 0) { sm.p1.red0[wid] = ceacc; sm.p1.red1[wid] = slacc; }
        __syncthreads();
        if (t == 0) {
            float c2 = 0.0f, s2 = 0.0f;
#pragma unroll
            for (int w2 = 0; w2 < 16; ++w2) { c2 += sm.p1.red0[w2]; s2 += sm.p1.red1[w2]; }
            cepart[bid] = c2;
            slpart[bid] = s2;
        }
    }

    // ---- ticket 1: signal phase-1 completion (device-scope release)
    __syncthreads();
    if (t == 0) {
        __threadfence();
        atomicAdd(&counter[0], 1u);
    }
    if (bid >= BATCH) return;                     // 192 blocks exit

    // ---- blocks 0..63: wait for all phase-1 writes, acquire
    if (t == 0) {
        while (__hip_atomic_load(&counter[0], __ATOMIC_ACQUIRE,
                                 __HIP_MEMORY_SCOPE_AGENT) < NBLKM)
            __builtin_amdgcn_s_sleep(16);
    }
    __syncthreads();
    __threadfence();

    // ================= PHASE 2 (R6 k_row, row = bid) =================
    const int row = bid;
    const unsigned* krow = keysg + (size_t)row * PRI;

    unsigned np = 0;
    for (int j = t; j < PRI; j += 1024) {
        const unsigned key = krow[j];
        sm.p2.keys[j] = key;
        np += (key == 0u) ? 1u : 0u;
    }
#pragma unroll
    for (int off = 32; off > 0; off >>= 1) np += __shfl_xor(np, off, 64);
    __syncthreads();
    if (lane == 0) sm.p2.ured[wid] = np;
    __syncthreads();
    unsigned num_pos = 0;
#pragma unroll
    for (int w = 0; w < 16; ++w) num_pos += sm.p2.ured[w];
    const int k = (int)num_pos * NEGPOS;

    unsigned Kstar = 0xFFFFFFFFu;
    int r_eq = 0;
    bool take_all = false;
    if (k > 0) {
        unsigned prefix = 0;
        int r = k, flag = 0;
        unsigned* hist_flat = &sm.p2.hist[0][0];
        for (int level = 3; level >= 0; --level) {
            const int shift = level * 8;
            for (int i = t; i < 16 * 257; i += 1024) hist_flat[i] = 0;
            __syncthreads();
            for (int j = t; j < PRI; j += 1024) {
                const unsigned key = sm.p2.keys[j];
                if (key == 0u) continue;
                if (level < 3 && (key >> (shift + 8)) != (prefix >> (shift + 8))) continue;
                atomicAdd(&sm.p2.hist[wid][(key >> shift) & 255u], 1u);
            }
            __syncthreads();
            if (wid == 0) {
                const int b0 = lane * 4;
                unsigned h0 = 0, h1 = 0, h2 = 0, h3 = 0;
#pragma unroll
                for (int w = 0; w < 16; ++w) {
                    h0 += sm.p2.hist[w][b0];     h1 += sm.p2.hist[w][b0 + 1];
                    h2 += sm.p2.hist[w][b0 + 2]; h3 += sm.p2.hist[w][b0 + 3];
                }
                const unsigned loc = h0 + h1 + h2 + h3;
                unsigned ssum = loc;                  // inclusive suffix scan
#pragma unroll
                for (int o2 = 1; o2 < 64; o2 <<= 1) {
                    const unsigned t2 = __shfl_down(ssum, o2, 64);
                    if (lane + o2 < 64) ssum += t2;
                }
                const unsigned above = ssum - loc;
                const unsigned cum3 = above + h3;
                const unsigned cum2 = cum3 + h2;
                const unsigned cum1 = cum2 + h1;
                const unsigned cum0 = cum1 + h0;
                const unsigned long long msk = __ballot(cum0 >= (unsigned)r);
                if (msk == 0ULL) {
                    if (lane == 0) sm.p2.sh_flag = 1;
                } else {
                    const int L = 63 - __clzll(msk);
                    if (lane == L) {
                        unsigned selbin, cumsel, hsel;
                        if      (cum3 >= (unsigned)r) { selbin = b0 + 3; cumsel = cum3; hsel = h3; }
                        else if (cum2 >= (unsigned)r) { selbin = b0 + 2; cumsel = cum2; hsel = h2; }
                        else if (cum1 >= (unsigned)r) { selbin = b0 + 1; cumsel = cum1; hsel = h1; }
                        else                          { selbin = b0;     cumsel = cum0; hsel = h0; }
                        sm.p2.sh_prefix = prefix | (selbin << shift);
                        sm.p2.sh_r = (unsigned)r - (cumsel - hsel);
                        sm.p2.sh_flag = 0;
                    }
                }
            }
            __syncthreads();
            flag = sm.p2.sh_flag;
            if (flag) break;
            prefix = sm.p2.sh_prefix;
            r = (int)sm.p2.sh_r;
            __syncthreads();
        }
        take_all = (flag != 0);
        if (!take_all) { Kstar = prefix; r_eq = r; }
    }

    float obj = 0.0f;
    if (k > 0) {
        for (int j = t; j < PRI; j += 1024) {
            const unsigned key = sm.p2.keys[j];
            if (key != 0u && (take_all || key > Kstar))
                obj += __uint_as_float(key ^ 0x80000000u);
        }
        if (t == 0 && !take_all)
            obj += (float)r_eq * __uint_as_float(Kstar ^ 0x80000000u);
    }

#pragma unroll
    for (int off = 32; off > 0; off >>= 1) obj += __shfl_xor(obj, off, 64);
    __syncthreads();
    if (lane == 0) sm.p2.fred[wid] = obj;
    __syncthreads();
    if (t == 0) {
        float to = 0.0f;
#pragma unroll
        for (int w = 0; w < 16; ++w) to += sm.p2.fred[w];
        rowobj[row] = to;
        rownp[row]  = (float)num_pos;
        __threadfence();
        const unsigned t2 = atomicAdd(&counter[1], 1u);
        sm.p2.sh_flag = (t2 == BATCH - 1) ? -1 : 0;
    }
    __syncthreads();
    if (sm.p2.sh_flag != -1) return;

    // ---- last row-block: final reduce
    __threadfence();
    float ce = 0.0f, sl = 0.0f, ro = 0.0f, np2 = 0.0f;
    if (t < NBLKM) { ce = cepart[t]; sl = slpart[t]; }
    if (t < BATCH) { ro = rowobj[t]; np2 = rownp[t]; }
#pragma unroll
    for (int off = 32; off > 0; off >>= 1) {
        ce  += __shfl_xor(ce,  off, 64);
        sl  += __shfl_xor(sl,  off, 64);
        ro  += __shfl_xor(ro,  off, 64);
        np2 += __shfl_xor(np2, off, 64);
    }
    __syncthreads();
    if (lane == 0) {
        sm.p2.fred[wid]  = ce + ro;
        sm.p2.fred2[wid] = sl;
        sm.p2.ured[wid]  = __float_as_uint(np2);
    }
    __syncthreads();
    if (t == 0) {
        float tobj = 0.0f, tsl = 0.0f, tnp = 0.0f;
#pragma unroll
        for (int w = 0; w < 16; ++w) {
            tobj += sm.p2.fred[w];
            tsl  += sm.p2.fred2[w];
            tnp  += __uint_as_float(sm.p2.ured[w]);
        }
        const float npos = fmaxf(tnp, 1.0f);
        out[0] = tobj / npos;
        out[1] = tsl / npos;
    }
}

extern "C" void kernel_launch(void* const* d_in, const int* in_sizes, int n_in,
                              void* d_out, int out_size, void* d_ws, size_t ws_size,
                              hipStream_t stream) {
    const float* pred_loc  = (const float*)d_in[0];
    const float* pred_conf = (const float*)d_in[1];
    const float* gt_loc    = (const float*)d_in[2];
    const int*   gt_labels = (const int*)d_in[3];
    float* out = (float*)d_out;

    unsigned* counter = (unsigned*)d_ws;                  // 2 u32 (16 B slot)
    unsigned* keysg   = (unsigned*)d_ws + 4;              // NTOT u32
    float*    cepart  = (float*)(keysg + NTOT);           // NBLKM f
    float*    slpart  = cepart + NBLKM;                   // NBLKM f
    float*    rowobj  = slpart + NBLKM;                   // BATCH f
    float*    rownp   = rowobj + BATCH;                   // BATCH f

    hipMemsetAsync(counter, 0, 16, stream);               // zero tickets
    k_all<<<NBLKM, 1024, 0, stream>>>(pred_conf, gt_labels, pred_loc, gt_loc,
                                      keysg, cepart, slpart, counter,
                                      rowobj, rownp, out);
}

// Round 11
// 77.309 us; speedup vs baseline: 1.2580x; 1.2580x over previous
//
#include <hip/hip_runtime.h>
#include <cstdint>
#include <cstddef>

#define BATCH 64
#define PRI   8732
#define NCLS  81
#define NEGPOS 3
#define NTOT  (BATCH * PRI)          // 558848
#define PPB   64                     // priors per window
#define NWIN  (NTOT / PPB)           // 8732 windows
#define WFLOATS (PPB * NCLS)         // 5184 floats per window
#define WF4   (WFLOATS / 4)          // 1296 float4s per window
#define NPERS 256                    // persistent k_lse blocks, 1/CU
#define WBASE (NWIN / NPERS)         // 34
#define WREM  (NWIN % NPERS)         // 28

__device__ __forceinline__ unsigned keymap(float f) {
    unsigned u = __float_as_uint(f);
    return (u & 0x80000000u) ? ~u : (u | 0x80000000u);
}

// async global->LDS, 16 B per lane (direct-to-LDS DMA, no VGPR round-trip)
__device__ __forceinline__ void gl_lds16(const float4* g, float4* l) {
    __builtin_amdgcn_global_load_lds(
        (const __attribute__((address_space(1))) void*)(const void*)g,
        (__attribute__((address_space(3))) void*)(void*)l, 16, 0, 0);
}

// ---------------------------------------------------------------------------
// Kernel 1: 256 persistent blocks x 256 threads, 1 block/CU. CHUNKED window
// assignment: block b owns a CONTIGUOUS span of windows (sequential ~707 KB
// read stream per CU — few, long DRAM streams instead of 768+ interleaved
// strided ones). Double-buffered LDS via global_load_lds (R6-proven);
// 4 threads/prior, aligned ds_read_b128, -inf edge masks, 2-shfl merge.
// ---------------------------------------------------------------------------
__global__ __launch_bounds__(256) void k_lse(const float* __restrict__ conf,
                                             const int* __restrict__ labels,
                                             const float* __restrict__ ploc,
                                             const float* __restrict__ gloc,
                                             unsigned* __restrict__ keysg,
                                             float* __restrict__ cepart,
                                             float* __restrict__ slpart) {
    __shared__ float lds[2][WFLOATS];       // 41472 B
    __shared__ int   labs[2][PPB];
    __shared__ float red0[4], red1[4];
    const int t = threadIdx.x;
    const int bid = blockIdx.x;

    // chunked span: blocks 0..WREM-1 take WBASE+1 windows, rest WBASE
    const int wstart = bid * WBASE + ((bid < WREM) ? bid : WREM);
    const int wcount = WBASE + ((bid < WREM) ? 1 : 0);

    float ceacc = 0.0f, slacc = 0.0f;

    auto stage = [&](int buf, int w) {
        const float4* g4 = reinterpret_cast<const float4*>(conf) + (size_t)w * WF4;
        float4* l4 = reinterpret_cast<float4*>(&lds[buf][0]);
#pragma unroll
        for (int j = 0; j < 5; ++j) gl_lds16(&g4[t + 256 * j], &l4[t + 256 * j]);
        if (t < WF4 - 1280) gl_lds16(&g4[t + 1280], &l4[t + 1280]);
        if (t < PPB) labs[buf][t] = labels[w * PPB + t];
    };

    stage(0, wstart);
    __syncthreads();                         // drain DMA for first window

    int cur = 0;
    for (int i = 0; ; ++i) {
        const int w = wstart + i;            // sequential stream
        const bool more = (i + 1 < wcount);
        if (more) stage(cur ^ 1, w + 1);     // DMA next window under compute

        const float* ldsw = &lds[cur][0];
        const int q   = t >> 2, h = t & 3;
        const int f0  = q * NCLS + 20 * h;
        const int len = (h == 3) ? 21 : 20;
        const int a0  = f0 & ~3;
        const int o   = f0 & 3;
        const int ve  = o + len;

        const float4* lp = reinterpret_cast<const float4*>(ldsw + a0);
        float4 v0 = lp[0], v1 = lp[1], v2 = lp[2], v3 = lp[3], v4 = lp[4], v5 = lp[5];
        v0.x = (o > 0) ? -INFINITY : v0.x;
        v0.y = (o > 1) ? -INFINITY : v0.y;
        v0.z = (o > 2) ? -INFINITY : v0.z;
        v5.x = (ve > 20) ? v5.x : -INFINITY;
        v5.y = (ve > 21) ? v5.y : -INFINITY;
        v5.z = (ve > 22) ? v5.z : -INFINITY;
        v5.w = (ve > 23) ? v5.w : -INFINITY;

        float m;
        {
            float a = fmaxf(fmaxf(v0.x, v0.y), fmaxf(v0.z, v0.w));
            float c = fmaxf(fmaxf(v1.x, v1.y), fmaxf(v1.z, v1.w));
            float d = fmaxf(fmaxf(v2.x, v2.y), fmaxf(v2.z, v2.w));
            float e = fmaxf(fmaxf(v3.x, v3.y), fmaxf(v3.z, v3.w));
            float f = fmaxf(fmaxf(v4.x, v4.y), fmaxf(v4.z, v4.w));
            float g = fmaxf(fmaxf(v5.x, v5.y), fmaxf(v5.z, v5.w));
            m = fmaxf(fmaxf(fmaxf(a, c), fmaxf(d, e)), fmaxf(f, g));
        }
        float s =
            __expf(v0.x - m) + __expf(v0.y - m) + __expf(v0.z - m) + __expf(v0.w - m) +
            __expf(v1.x - m) + __expf(v1.y - m) + __expf(v1.z - m) + __expf(v1.w - m) +
            __expf(v2.x - m) + __expf(v2.y - m) + __expf(v2.z - m) + __expf(v2.w - m) +
            __expf(v3.x - m) + __expf(v3.y - m) + __expf(v3.z - m) + __expf(v3.w - m) +
            __expf(v4.x - m) + __expf(v4.y - m) + __expf(v4.z - m) + __expf(v4.w - m) +
            __expf(v5.x - m) + __expf(v5.y - m) + __expf(v5.z - m) + __expf(v5.w - m);

#pragma unroll
        for (int off = 1; off <= 2; off <<= 1) {
            const float mo = __shfl_xor(m, off, 64);
            const float so = __shfl_xor(s, off, 64);
            const float mn = fmaxf(m, mo);
            s = s * __expf(m - mn) + so * __expf(mo - mn);
            m = mn;
        }
        const float lse = m + __logf(s);

        if (h == 0) {
            const int p   = w * PPB + q;
            const int lab = labs[cur][q];
            const float c0 = ldsw[q * NCLS];
            unsigned key = 0u;
            if (lab > 0) {
                ceacc += lse - ldsw[q * NCLS + lab];
                const float4 pl = *reinterpret_cast<const float4*>(ploc + (size_t)p * 4);
                const float4 gl = *reinterpret_cast<const float4*>(gloc + (size_t)p * 4);
                float d, a;
                d = pl.x - gl.x; a = fabsf(d); slacc += (a < 1.0f) ? 0.5f * d * d : a - 0.5f;
                d = pl.y - gl.y; a = fabsf(d); slacc += (a < 1.0f) ? 0.5f * d * d : a - 0.5f;
                d = pl.z - gl.z; a = fabsf(d); slacc += (a < 1.0f) ? 0.5f * d * d : a - 0.5f;
                d = pl.w - gl.w; a = fabsf(d); slacc += (a < 1.0f) ? 0.5f * d * d : a - 0.5f;
            } else {
                key = keymap(lse - c0);       // bg >= 0 -> key >= 0x80000000
            }
            keysg[p] = key;
        }

        if (!more) break;
        __syncthreads();                      // waits DMA(w+1) + readers of cur
        cur ^= 1;
    }

#pragma unroll
    for (int off = 32; off > 0; off >>= 1) {
        ceacc += __shfl_xor(ceacc, off, 64);
        slacc += __shfl_xor(slacc, off, 64);
    }
    const int wid = t >> 6, lane = t & 63;
    __syncthreads();
    if (lane == 0) { red0[wid] = ceacc; red1[wid] = slacc; }
    __syncthreads();
    if (t == 0) {
        cepart[bid] = red0[0] + red0[1] + red0[2] + red0[3];
        slpart[bid] = red1[0] + red1[1] + red1[2] + red1[3];
    }
}

// ---------------------------------------------------------------------------
// Kernel 2 (bit-identical to R6): one block (1024 thr) per batch row,
// keys-only input, wave-private LDS histograms, exact 4x8-bit radix select,
// selected sum reconstructed from keys.
// ---------------------------------------------------------------------------
__global__ __launch_bounds__(1024) void k_row(const unsigned* __restrict__ keysg,
                                              float* __restrict__ rowobj,
                                              float* __restrict__ rownp) {
    __shared__ unsigned keys_s[PRI];            // 34928 B
    __shared__ unsigned hist[16][257];          // wave-private, padded
    __shared__ unsigned ured[16];
    __shared__ float    fred[16];
    __shared__ unsigned sh_prefix, sh_r;
    __shared__ int      sh_flag;

    const int row  = blockIdx.x;
    const int tid  = threadIdx.x;
    const int wid  = tid >> 6;
    const int lane = tid & 63;
    const unsigned* krow = keysg + (size_t)row * PRI;

    unsigned np = 0;
    for (int j = tid; j < PRI; j += 1024) {
        const unsigned key = krow[j];
        keys_s[j] = key;
        np += (key == 0u) ? 1u : 0u;
    }
#pragma unroll
    for (int off = 32; off > 0; off >>= 1) np += __shfl_xor(np, off, 64);
    if (lane == 0) ured[wid] = np;
    __syncthreads();
    unsigned num_pos = 0;
#pragma unroll
    for (int w = 0; w < 16; ++w) num_pos += ured[w];
    const int k = (int)num_pos * NEGPOS;

    unsigned Kstar = 0xFFFFFFFFu;
    int r_eq = 0;
    bool take_all = false;
    if (k > 0) {
        unsigned prefix = 0;
        int r = k, flag = 0;
        unsigned* hist_flat = &hist[0][0];
        for (int level = 3; level >= 0; --level) {
            const int shift = level * 8;
            for (int i = tid; i < 16 * 257; i += 1024) hist_flat[i] = 0;
            __syncthreads();
            for (int j = tid; j < PRI; j += 1024) {
                const unsigned key = keys_s[j];
                if (key == 0u) continue;
                if (level < 3 && (key >> (shift + 8)) != (prefix >> (shift + 8))) continue;
                atomicAdd(&hist[wid][(key >> shift) & 255u], 1u);
            }
            __syncthreads();
            if (wid == 0) {
                const int b0 = lane * 4;
                unsigned h0 = 0, h1 = 0, h2 = 0, h3 = 0;
#pragma unroll
                for (int w = 0; w < 16; ++w) {
                    h0 += hist[w][b0]; h1 += hist[w][b0 + 1];
                    h2 += hist[w][b0 + 2]; h3 += hist[w][b0 + 3];
                }
                const unsigned loc = h0 + h1 + h2 + h3;
                unsigned ssum = loc;
#pragma unroll
                for (int o2 = 1; o2 < 64; o2 <<= 1) {
                    const unsigned t2 = __shfl_down(ssum, o2, 64);
                    if (lane + o2 < 64) ssum += t2;
                }
                const unsigned above = ssum - loc;
                const unsigned cum3 = above + h3;
                const unsigned cum2 = cum3 + h2;
                const unsigned cum1 = cum2 + h1;
                const unsigned cum0 = cum1 + h0;
                const unsigned long long msk = __ballot(cum0 >= (unsigned)r);
                if (msk == 0ULL) {
                    if (lane == 0) sh_flag = 1;
                } else {
                    const int L = 63 - __clzll(msk);
                    if (lane == L) {
                        unsigned selbin, cumsel, hsel;
                        if      (cum3 >= (unsigned)r) { selbin = b0 + 3; cumsel = cum3; hsel = h3; }
                        else if (cum2 >= (unsigned)r) { selbin = b0 + 2; cumsel = cum2; hsel = h2; }
                        else if (cum1 >= (unsigned)r) { selbin = b0 + 1; cumsel = cum1; hsel = h1; }
                        else                          { selbin = b0;     cumsel = cum0; hsel = h0; }
                        sh_prefix = prefix | (selbin << shift);
                        sh_r = (unsigned)r - (cumsel - hsel);
                        sh_flag = 0;
                    }
                }
            }
            __syncthreads();
            flag = sh_flag;
            if (flag) break;
            prefix = sh_prefix;
            r = (int)sh_r;
        }
        take_all = (flag != 0);
        if (!take_all) { Kstar = prefix; r_eq = r; }
    }

    float obj = 0.0f;
    if (k > 0) {
        for (int j = tid; j < PRI; j += 1024) {
            const unsigned key = keys_s[j];
            if (key != 0u && (take_all || key > Kstar))
                obj += __uint_as_float(key ^ 0x80000000u);
        }
        if (tid == 0 && !take_all)
            obj += (float)r_eq * __uint_as_float(Kstar ^ 0x80000000u);
    }

#pragma unroll
    for (int off = 32; off > 0; off >>= 1) obj += __shfl_xor(obj, off, 64);
    __syncthreads();
    if (lane == 0) fred[wid] = obj;
    __syncthreads();
    if (tid == 0) {
        float to = 0.0f;
#pragma unroll
        for (int w = 0; w < 16; ++w) to += fred[w];
        rowobj[row] = to;
        rownp[row]  = (float)num_pos;
    }
}

// ---------------------------------------------------------------------------
// Kernel 3: final reduction -> 2 scalars (NPERS + BATCH inputs)
// ---------------------------------------------------------------------------
__global__ __launch_bounds__(256) void k_final(const float* __restrict__ cepart,
                                               const float* __restrict__ slpart,
                                               const float* __restrict__ rowobj,
                                               const float* __restrict__ rownp,
                                               float* __restrict__ out) {
    const int tid = threadIdx.x;
    float ce = 0.0f, sl = 0.0f;
    for (int i = tid; i < NPERS; i += 256) { ce += cepart[i]; sl += slpart[i]; }
    float ro = 0.0f, np = 0.0f;
    if (tid < BATCH) { ro = rowobj[tid]; np = rownp[tid]; }
#pragma unroll
    for (int off = 32; off > 0; off >>= 1) {
        ce += __shfl_xor(ce, off, 64);
        sl += __shfl_xor(sl, off, 64);
        ro += __shfl_xor(ro, off, 64);
        np += __shfl_xor(np, off, 64);
    }
    __shared__ float r0[4], r1[4], r2[4], r3[4];
    const int wid = tid >> 6, lane = tid & 63;
    if (lane == 0) { r0[wid] = ce; r1[wid] = sl; r2[wid] = ro; r3[wid] = np; }
    __syncthreads();
    if (tid == 0) {
        const float tce = r0[0] + r0[1] + r0[2] + r0[3];
        const float tsl = r1[0] + r1[1] + r1[2] + r1[3];
        const float tro = r2[0] + r2[1] + r2[2] + r2[3];
        const float tnp = r3[0] + r3[1] + r3[2] + r3[3];
        const float npos = fmaxf(tnp, 1.0f);
        out[0] = (tce + tro) / npos;
        out[1] = tsl / npos;
    }
}

extern "C" void kernel_launch(void* const* d_in, const int* in_sizes, int n_in,
                              void* d_out, int out_size, void* d_ws, size_t ws_size,
                              hipStream_t stream) {
    const float* pred_loc  = (const float*)d_in[0];
    const float* pred_conf = (const float*)d_in[1];
    const float* gt_loc    = (const float*)d_in[2];
    const int*   gt_labels = (const int*)d_in[3];
    float* out = (float*)d_out;

    unsigned* keysg   = (unsigned*)d_ws;                  // NTOT u32
    float*    cepart  = (float*)(keysg + NTOT);           // NPERS f
    float*    slpart  = cepart + NPERS;                   // NPERS f
    float*    rowobj  = slpart + NPERS;                   // BATCH f
    float*    rownp   = rowobj + BATCH;                   // BATCH f

    k_lse<<<NPERS, 256, 0, stream>>>(pred_conf, gt_labels, pred_loc, gt_loc,
                                     keysg, cepart, slpart);
    k_row<<<BATCH, 1024, 0, stream>>>(keysg, rowobj, rownp);
    k_final<<<1, 256, 0, stream>>>(cepart, slpart, rowobj, rownp, out);
}

// Round 12
// 57.475 us; speedup vs baseline: 1.6921x; 1.3451x over previous
//
#include <hip/hip_runtime.h>
#include <cstdint>
#include <cstddef>

#define BATCH 64
#define PRI   8732
#define NCLS  81
#define NEGPOS 3
#define NTOT  (BATCH * PRI)          // 558848
#define PPB   64                     // priors per window
#define NWIN  (NTOT / PPB)           // 8732 windows
#define WFLOATS (PPB * NCLS)         // 5184 floats per window
#define WF4   (WFLOATS / 4)          // 1296 float4s per window
#define NPERS 768                    // persistent k_lse blocks (3/CU, LDS-lim)

__device__ __forceinline__ unsigned keymap(float f) {
    unsigned u = __float_as_uint(f);
    return (u & 0x80000000u) ? ~u : (u | 0x80000000u);
}

// async global->LDS, 16 B per lane (direct-to-LDS DMA, no VGPR round-trip)
__device__ __forceinline__ void gl_lds16(const float4* g, float4* l) {
    __builtin_amdgcn_global_load_lds(
        (const __attribute__((address_space(1))) void*)(const void*)g,
        (__attribute__((address_space(3))) void*)(void*)l, 16, 0, 0);
}

// ---------------------------------------------------------------------------
// Kernel 1 (bit-exact R6 best): 768 persistent blocks x 256 threads,
// 3 blocks/CU. Windows of 64 priors (20.7 KB), double-buffered LDS via
// global_load_lds; 4 threads/prior, aligned ds_read_b128, -inf edge masks,
// 2-shfl (m,s) merge. Keymapped bg keys (positives -> 0), per-block
// positive-ce / smooth-L1 partials.
// ---------------------------------------------------------------------------
__global__ __launch_bounds__(256) void k_lse(const float* __restrict__ conf,
                                             const int* __restrict__ labels,
                                             const float* __restrict__ ploc,
                                             const float* __restrict__ gloc,
                                             unsigned* __restrict__ keysg,
                                             float* __restrict__ cepart,
                                             float* __restrict__ slpart) {
    __shared__ float lds[2][WFLOATS];       // 41472 B
    __shared__ int   labs[2][PPB];
    __shared__ float red0[4], red1[4];
    const int t = threadIdx.x;
    const int bid = blockIdx.x;

    float ceacc = 0.0f, slacc = 0.0f;

    auto stage = [&](int buf, int w) {
        const float4* g4 = reinterpret_cast<const float4*>(conf) + (size_t)w * WF4;
        float4* l4 = reinterpret_cast<float4*>(&lds[buf][0]);
#pragma unroll
        for (int j = 0; j < 5; ++j) gl_lds16(&g4[t + 256 * j], &l4[t + 256 * j]);
        if (t < WF4 - 1280) gl_lds16(&g4[t + 1280], &l4[t + 1280]);
        if (t < PPB) labs[buf][t] = labels[w * PPB + t];
    };

    stage(0, bid);
    __syncthreads();                         // drain DMA for first window

    int cur = 0;
    for (int i = 0; ; ++i) {
        const int w  = bid + i * NPERS;
        const int wn = w + NPERS;
        const bool more = (wn < NWIN);
        if (more) stage(cur ^ 1, wn);        // DMA next window under compute

        const float* ldsw = &lds[cur][0];
        const int q   = t >> 2, h = t & 3;
        const int f0  = q * NCLS + 20 * h;
        const int len = (h == 3) ? 21 : 20;
        const int a0  = f0 & ~3;
        const int o   = f0 & 3;
        const int ve  = o + len;

        const float4* lp = reinterpret_cast<const float4*>(ldsw + a0);
        float4 v0 = lp[0], v1 = lp[1], v2 = lp[2], v3 = lp[3], v4 = lp[4], v5 = lp[5];
        v0.x = (o > 0) ? -INFINITY : v0.x;
        v0.y = (o > 1) ? -INFINITY : v0.y;
        v0.z = (o > 2) ? -INFINITY : v0.z;
        v5.x = (ve > 20) ? v5.x : -INFINITY;
        v5.y = (ve > 21) ? v5.y : -INFINITY;
        v5.z = (ve > 22) ? v5.z : -INFINITY;
        v5.w = (ve > 23) ? v5.w : -INFINITY;

        float m;
        {
            float a = fmaxf(fmaxf(v0.x, v0.y), fmaxf(v0.z, v0.w));
            float c = fmaxf(fmaxf(v1.x, v1.y), fmaxf(v1.z, v1.w));
            float d = fmaxf(fmaxf(v2.x, v2.y), fmaxf(v2.z, v2.w));
            float e = fmaxf(fmaxf(v3.x, v3.y), fmaxf(v3.z, v3.w));
            float f = fmaxf(fmaxf(v4.x, v4.y), fmaxf(v4.z, v4.w));
            float g = fmaxf(fmaxf(v5.x, v5.y), fmaxf(v5.z, v5.w));
            m = fmaxf(fmaxf(fmaxf(a, c), fmaxf(d, e)), fmaxf(f, g));
        }
        float s =
            __expf(v0.x - m) + __expf(v0.y - m) + __expf(v0.z - m) + __expf(v0.w - m) +
            __expf(v1.x - m) + __expf(v1.y - m) + __expf(v1.z - m) + __expf(v1.w - m) +
            __expf(v2.x - m) + __expf(v2.y - m) + __expf(v2.z - m) + __expf(v2.w - m) +
            __expf(v3.x - m) + __expf(v3.y - m) + __expf(v3.z - m) + __expf(v3.w - m) +
            __expf(v4.x - m) + __expf(v4.y - m) + __expf(v4.z - m) + __expf(v4.w - m) +
            __expf(v5.x - m) + __expf(v5.y - m) + __expf(v5.z - m) + __expf(v5.w - m);

#pragma unroll
        for (int off = 1; off <= 2; off <<= 1) {
            const float mo = __shfl_xor(m, off, 64);
            const float so = __shfl_xor(s, off, 64);
            const float mn = fmaxf(m, mo);
            s = s * __expf(m - mn) + so * __expf(mo - mn);
            m = mn;
        }
        const float lse = m + __logf(s);

        if (h == 0) {
            const int p   = w * PPB + q;
            const int lab = labs[cur][q];
            const float c0 = ldsw[q * NCLS];
            unsigned key = 0u;
            if (lab > 0) {
                ceacc += lse - ldsw[q * NCLS + lab];
                const float4 pl = *reinterpret_cast<const float4*>(ploc + (size_t)p * 4);
                const float4 gl = *reinterpret_cast<const float4*>(gloc + (size_t)p * 4);
                float d, a;
                d = pl.x - gl.x; a = fabsf(d); slacc += (a < 1.0f) ? 0.5f * d * d : a - 0.5f;
                d = pl.y - gl.y; a = fabsf(d); slacc += (a < 1.0f) ? 0.5f * d * d : a - 0.5f;
                d = pl.z - gl.z; a = fabsf(d); slacc += (a < 1.0f) ? 0.5f * d * d : a - 0.5f;
                d = pl.w - gl.w; a = fabsf(d); slacc += (a < 1.0f) ? 0.5f * d * d : a - 0.5f;
            } else {
                key = keymap(lse - c0);       // bg >= 0 -> key >= 0x80000000
            }
            keysg[p] = key;
        }

        if (!more) break;
        __syncthreads();                      // waits DMA(wn) + readers of cur
        cur ^= 1;
    }

#pragma unroll
    for (int off = 32; off > 0; off >>= 1) {
        ceacc += __shfl_xor(ceacc, off, 64);
        slacc += __shfl_xor(slacc, off, 64);
    }
    const int wid = t >> 6, lane = t & 63;
    __syncthreads();
    if (lane == 0) { red0[wid] = ceacc; red1[wid] = slacc; }
    __syncthreads();
    if (t == 0) {
        cepart[bid] = red0[0] + red0[1] + red0[2] + red0[3];
        slpart[bid] = red1[0] + red1[1] + red1[2] + red1[3];
    }
}

// ---------------------------------------------------------------------------
// Kernel 2 (bit-identical to R6): one block (1024 thr) per batch row,
// keys-only input, wave-private LDS histograms, exact 4x8-bit radix select,
// selected sum reconstructed from keys.
// ---------------------------------------------------------------------------
__global__ __launch_bounds__(1024) void k_row(const unsigned* __restrict__ keysg,
                                              float* __restrict__ rowobj,
                                              float* __restrict__ rownp) {
    __shared__ unsigned keys_s[PRI];            // 34928 B
    __shared__ unsigned hist[16][257];          // wave-private, padded
    __shared__ unsigned ured[16];
    __shared__ float    fred[16];
    __shared__ unsigned sh_prefix, sh_r;
    __shared__ int      sh_flag;

    const int row  = blockIdx.x;
    const int tid  = threadIdx.x;
    const int wid  = tid >> 6;
    const int lane = tid & 63;
    const unsigned* krow = keysg + (size_t)row * PRI;

    unsigned np = 0;
    for (int j = tid; j < PRI; j += 1024) {
        const unsigned key = krow[j];
        keys_s[j] = key;
        np += (key == 0u) ? 1u : 0u;
    }
#pragma unroll
    for (int off = 32; off > 0; off >>= 1) np += __shfl_xor(np, off, 64);
    if (lane == 0) ured[wid] = np;
    __syncthreads();
    unsigned num_pos = 0;
#pragma unroll
    for (int w = 0; w < 16; ++w) num_pos += ured[w];
    const int k = (int)num_pos * NEGPOS;

    unsigned Kstar = 0xFFFFFFFFu;
    int r_eq = 0;
    bool take_all = false;
    if (k > 0) {
        unsigned prefix = 0;
        int r = k, flag = 0;
        unsigned* hist_flat = &hist[0][0];
        for (int level = 3; level >= 0; --level) {
            const int shift = level * 8;
            for (int i = tid; i < 16 * 257; i += 1024) hist_flat[i] = 0;
            __syncthreads();
            for (int j = tid; j < PRI; j += 1024) {
                const unsigned key = keys_s[j];
                if (key == 0u) continue;
                if (level < 3 && (key >> (shift + 8)) != (prefix >> (shift + 8))) continue;
                atomicAdd(&hist[wid][(key >> shift) & 255u], 1u);
            }
            __syncthreads();
            if (wid == 0) {
                const int b0 = lane * 4;
                unsigned h0 = 0, h1 = 0, h2 = 0, h3 = 0;
#pragma unroll
                for (int w = 0; w < 16; ++w) {
                    h0 += hist[w][b0]; h1 += hist[w][b0 + 1];
                    h2 += hist[w][b0 + 2]; h3 += hist[w][b0 + 3];
                }
                const unsigned loc = h0 + h1 + h2 + h3;
                unsigned ssum = loc;
#pragma unroll
                for (int o2 = 1; o2 < 64; o2 <<= 1) {
                    const unsigned t2 = __shfl_down(ssum, o2, 64);
                    if (lane + o2 < 64) ssum += t2;
                }
                const unsigned above = ssum - loc;
                const unsigned cum3 = above + h3;
                const unsigned cum2 = cum3 + h2;
                const unsigned cum1 = cum2 + h1;
                const unsigned cum0 = cum1 + h0;
                const unsigned long long msk = __ballot(cum0 >= (unsigned)r);
                if (msk == 0ULL) {
                    if (lane == 0) sh_flag = 1;
                } else {
                    const int L = 63 - __clzll(msk);
                    if (lane == L) {
                        unsigned selbin, cumsel, hsel;
                        if      (cum3 >= (unsigned)r) { selbin = b0 + 3; cumsel = cum3; hsel = h3; }
                        else if (cum2 >= (unsigned)r) { selbin = b0 + 2; cumsel = cum2; hsel = h2; }
                        else if (cum1 >= (unsigned)r) { selbin = b0 + 1; cumsel = cum1; hsel = h1; }
                        else                          { selbin = b0;     cumsel = cum0; hsel = h0; }
                        sh_prefix = prefix | (selbin << shift);
                        sh_r = (unsigned)r - (cumsel - hsel);
                        sh_flag = 0;
                    }
                }
            }
            __syncthreads();
            flag = sh_flag;
            if (flag) break;
            prefix = sh_prefix;
            r = (int)sh_r;
        }
        take_all = (flag != 0);
        if (!take_all) { Kstar = prefix; r_eq = r; }
    }

    float obj = 0.0f;
    if (k > 0) {
        for (int j = tid; j < PRI; j += 1024) {
            const unsigned key = keys_s[j];
            if (key != 0u && (take_all || key > Kstar))
                obj += __uint_as_float(key ^ 0x80000000u);
        }
        if (tid == 0 && !take_all)
            obj += (float)r_eq * __uint_as_float(Kstar ^ 0x80000000u);
    }

#pragma unroll
    for (int off = 32; off > 0; off >>= 1) obj += __shfl_xor(obj, off, 64);
    __syncthreads();
    if (lane == 0) fred[wid] = obj;
    __syncthreads();
    if (tid == 0) {
        float to = 0.0f;
#pragma unroll
        for (int w = 0; w < 16; ++w) to += fred[w];
        rowobj[row] = to;
        rownp[row]  = (float)num_pos;
    }
}

// ---------------------------------------------------------------------------
// Kernel 3 (bit-identical to R6): final reduction -> 2 scalars
// ---------------------------------------------------------------------------
__global__ __launch_bounds__(256) void k_final(const float* __restrict__ cepart,
                                               const float* __restrict__ slpart,
                                               const float* __restrict__ rowobj,
                                               const float* __restrict__ rownp,
                                               float* __restrict__ out) {
    const int tid = threadIdx.x;
    float ce = 0.0f, sl = 0.0f;
    for (int i = tid; i < NPERS; i += 256) { ce += cepart[i]; sl += slpart[i]; }
    float ro = 0.0f, np = 0.0f;
    if (tid < BATCH) { ro = rowobj[tid]; np = rownp[tid]; }
#pragma unroll
    for (int off = 32; off > 0; off >>= 1) {
        ce += __shfl_xor(ce, off, 64);
        sl += __shfl_xor(sl, off, 64);
        ro += __shfl_xor(ro, off, 64);
        np += __shfl_xor(np, off, 64);
    }
    __shared__ float r0[4], r1[4], r2[4], r3[4];
    const int wid = tid >> 6, lane = tid & 63;
    if (lane == 0) { r0[wid] = ce; r1[wid] = sl; r2[wid] = ro; r3[wid] = np; }
    __syncthreads();
    if (tid == 0) {
        const float tce = r0[0] + r0[1] + r0[2] + r0[3];
        const float tsl = r1[0] + r1[1] + r1[2] + r1[3];
        const float tro = r2[0] + r2[1] + r2[2] + r2[3];
        const float tnp = r3[0] + r3[1] + r3[2] + r3[3];
        const float npos = fmaxf(tnp, 1.0f);
        out[0] = (tce + tro) / npos;
        out[1] = tsl / npos;
    }
}

extern "C" void kernel_launch(void* const* d_in, const int* in_sizes, int n_in,
                              void* d_out, int out_size, void* d_ws, size_t ws_size,
                              hipStream_t stream) {
    const float* pred_loc  = (const float*)d_in[0];
    const float* pred_conf = (const float*)d_in[1];
    const float* gt_loc    = (const float*)d_in[2];
    const int*   gt_labels = (const int*)d_in[3];
    float* out = (float*)d_out;

    unsigned* keysg   = (unsigned*)d_ws;                  // NTOT u32
    float*    cepart  = (float*)(keysg + NTOT);           // NPERS f
    float*    slpart  = cepart + NPERS;                   // NPERS f
    float*    rowobj  = slpart + NPERS;                   // BATCH f
    float*    rownp   = rowobj + BATCH;                   // BATCH f

    k_lse<<<NPERS, 256, 0, stream>>>(pred_conf, gt_labels, pred_loc, gt_loc,
                                     keysg, cepart, slpart);
    k_row<<<BATCH, 1024, 0, stream>>>(keysg, rowobj, rownp);
    k_final<<<1, 256, 0, stream>>>(cepart, slpart, rowobj, rownp, out);
}

// Round 13
// 56.812 us; speedup vs baseline: 1.7118x; 1.0117x over previous
//
#include <hip/hip_runtime.h>
#include <cstdint>
#include <cstddef>

#define BATCH 64
#define PRI   8732
#define NCLS  81
#define NEGPOS 3
#define NTOT  (BATCH * PRI)          // 558848
#define PPB   64                     // priors per window
#define NWIN  (NTOT / PPB)           // 8732 windows
#define WFLOATS (PPB * NCLS)         // 5184 floats per window
#define WF4   (WFLOATS / 4)          // 1296 float4s per window
#define NPERS 768                    // persistent k_lse blocks (3/CU)

__device__ __forceinline__ unsigned keymap(float f) {
    unsigned u = __float_as_uint(f);
    return (u & 0x80000000u) ? ~u : (u | 0x80000000u);
}

// ---------------------------------------------------------------------------
// Kernel 1 (R12 shape, read path swapped): 768 persistent blocks x 256 thr,
// 3 blocks/CU. SINGLE-buffered 21 KB LDS window; staging is now
// buffer_load->VGPR (6 coalesced float4/thread) issued one window AHEAD,
// written to LDS after the compute barrier (T14 issue-early/write-late).
// Tests whether the ~4 TB/s plateau is specific to the global_load_lds DMA
// path. Compute identical to R6: 4 threads/prior, aligned ds_read_b128,
// -inf edge masks, 2-shfl (m,s) merge.
// ---------------------------------------------------------------------------
__global__ __launch_bounds__(256) void k_lse(const float* __restrict__ conf,
                                             const int* __restrict__ labels,
                                             const float* __restrict__ ploc,
                                             const float* __restrict__ gloc,
                                             unsigned* __restrict__ keysg,
                                             float* __restrict__ cepart,
                                             float* __restrict__ slpart) {
    __shared__ float lds[WFLOATS];          // 20736 B (single buffer)
    __shared__ int   labs[PPB];
    __shared__ float red0[4], red1[4];
    const int t = threadIdx.x;
    const int bid = blockIdx.x;

    float ceacc = 0.0f, slacc = 0.0f;

    const float4* conf4 = reinterpret_cast<const float4*>(conf);
    float4 r0 = {0,0,0,0}, r1 = r0, r2 = r0, r3 = r0, r4 = r0, r5 = r0;
    int labr = 0;

    auto loadreg = [&](int w) {             // issue 5-6 coalesced float4 loads
        const float4* g4 = conf4 + (size_t)w * WF4;
        r0 = g4[t];
        r1 = g4[t + 256];
        r2 = g4[t + 512];
        r3 = g4[t + 768];
        r4 = g4[t + 1024];
        if (t < WF4 - 1280) r5 = g4[t + 1280];      // 16 threads
        if (t < PPB) labr = labels[w * PPB + t];
    };
    auto writelds = [&]() {                 // compiler inserts vmcnt wait here
        float4* l4 = reinterpret_cast<float4*>(lds);
        l4[t]        = r0;
        l4[t + 256]  = r1;
        l4[t + 512]  = r2;
        l4[t + 768]  = r3;
        l4[t + 1024] = r4;
        if (t < WF4 - 1280) l4[t + 1280] = r5;
        if (t < PPB) labs[t] = labr;
    };

    // prologue: LDS <- window bid; regs <- window bid+NPERS (in flight)
    loadreg(bid);
    writelds();
    if (bid + NPERS < NWIN) loadreg(bid + NPERS);
    __syncthreads();

    for (int i = 0; ; ++i) {
        const int w  = bid + i * NPERS;
        const int wn = w + NPERS;
        const bool more = (wn < NWIN);

        // ---- compute window w from LDS (identical to R6)
        const int q   = t >> 2, h = t & 3;
        const int f0  = q * NCLS + 20 * h;
        const int len = (h == 3) ? 21 : 20;
        const int a0  = f0 & ~3;
        const int o   = f0 & 3;
        const int ve  = o + len;

        const float4* lp = reinterpret_cast<const float4*>(lds + a0);
        float4 v0 = lp[0], v1 = lp[1], v2 = lp[2], v3 = lp[3], v4 = lp[4], v5 = lp[5];
        v0.x = (o > 0) ? -INFINITY : v0.x;
        v0.y = (o > 1) ? -INFINITY : v0.y;
        v0.z = (o > 2) ? -INFINITY : v0.z;
        v5.x = (ve > 20) ? v5.x : -INFINITY;
        v5.y = (ve > 21) ? v5.y : -INFINITY;
        v5.z = (ve > 22) ? v5.z : -INFINITY;
        v5.w = (ve > 23) ? v5.w : -INFINITY;

        float m;
        {
            float a = fmaxf(fmaxf(v0.x, v0.y), fmaxf(v0.z, v0.w));
            float c = fmaxf(fmaxf(v1.x, v1.y), fmaxf(v1.z, v1.w));
            float d = fmaxf(fmaxf(v2.x, v2.y), fmaxf(v2.z, v2.w));
            float e = fmaxf(fmaxf(v3.x, v3.y), fmaxf(v3.z, v3.w));
            float f = fmaxf(fmaxf(v4.x, v4.y), fmaxf(v4.z, v4.w));
            float g = fmaxf(fmaxf(v5.x, v5.y), fmaxf(v5.z, v5.w));
            m = fmaxf(fmaxf(fmaxf(a, c), fmaxf(d, e)), fmaxf(f, g));
        }
        float s =
            __expf(v0.x - m) + __expf(v0.y - m) + __expf(v0.z - m) + __expf(v0.w - m) +
            __expf(v1.x - m) + __expf(v1.y - m) + __expf(v1.z - m) + __expf(v1.w - m) +
            __expf(v2.x - m) + __expf(v2.y - m) + __expf(v2.z - m) + __expf(v2.w - m) +
            __expf(v3.x - m) + __expf(v3.y - m) + __expf(v3.z - m) + __expf(v3.w - m) +
            __expf(v4.x - m) + __expf(v4.y - m) + __expf(v4.z - m) + __expf(v4.w - m) +
            __expf(v5.x - m) + __expf(v5.y - m) + __expf(v5.z - m) + __expf(v5.w - m);

#pragma unroll
        for (int off = 1; off <= 2; off <<= 1) {
            const float mo = __shfl_xor(m, off, 64);
            const float so = __shfl_xor(s, off, 64);
            const float mn = fmaxf(m, mo);
            s = s * __expf(m - mn) + so * __expf(mo - mn);
            m = mn;
        }
        const float lse = m + __logf(s);

        if (h == 0) {
            const int p   = w * PPB + q;
            const int lab = labs[q];
            const float c0 = lds[q * NCLS];
            unsigned key = 0u;
            if (lab > 0) {
                ceacc += lse - lds[q * NCLS + lab];
                const float4 pl = *reinterpret_cast<const float4*>(ploc + (size_t)p * 4);
                const float4 gl = *reinterpret_cast<const float4*>(gloc + (size_t)p * 4);
                float d, a;
                d = pl.x - gl.x; a = fabsf(d); slacc += (a < 1.0f) ? 0.5f * d * d : a - 0.5f;
                d = pl.y - gl.y; a = fabsf(d); slacc += (a < 1.0f) ? 0.5f * d * d : a - 0.5f;
                d = pl.z - gl.z; a = fabsf(d); slacc += (a < 1.0f) ? 0.5f * d * d : a - 0.5f;
                d = pl.w - gl.w; a = fabsf(d); slacc += (a < 1.0f) ? 0.5f * d * d : a - 0.5f;
            } else {
                key = keymap(lse - c0);       // bg >= 0 -> key >= 0x80000000
            }
            keysg[p] = key;
        }

        if (!more) break;
        __syncthreads();                      // all readers done with LDS
        writelds();                           // window wn (waits its loads)
        if (wn + NPERS < NWIN) loadreg(wn + NPERS);   // issue next-next
        __syncthreads();                      // LDS(wn) visible to all
    }

#pragma unroll
    for (int off = 32; off > 0; off >>= 1) {
        ceacc += __shfl_xor(ceacc, off, 64);
        slacc += __shfl_xor(slacc, off, 64);
    }
    const int wid = t >> 6, lane = t & 63;
    __syncthreads();
    if (lane == 0) { red0[wid] = ceacc; red1[wid] = slacc; }
    __syncthreads();
    if (t == 0) {
        cepart[bid] = red0[0] + red0[1] + red0[2] + red0[3];
        slpart[bid] = red1[0] + red1[1] + red1[2] + red1[3];
    }
}

// ---------------------------------------------------------------------------
// Kernel 2 (bit-identical to R6/R12): one block (1024 thr) per batch row,
// keys-only input, wave-private LDS histograms, exact 4x8-bit radix select,
// selected sum reconstructed from keys.
// ---------------------------------------------------------------------------
__global__ __launch_bounds__(1024) void k_row(const unsigned* __restrict__ keysg,
                                              float* __restrict__ rowobj,
                                              float* __restrict__ rownp) {
    __shared__ unsigned keys_s[PRI];            // 34928 B
    __shared__ unsigned hist[16][257];          // wave-private, padded
    __shared__ unsigned ured[16];
    __shared__ float    fred[16];
    __shared__ unsigned sh_prefix, sh_r;
    __shared__ int      sh_flag;

    const int row  = blockIdx.x;
    const int tid  = threadIdx.x;
    const int wid  = tid >> 6;
    const int lane = tid & 63;
    const unsigned* krow = keysg + (size_t)row * PRI;

    unsigned np = 0;
    for (int j = tid; j < PRI; j += 1024) {
        const unsigned key = krow[j];
        keys_s[j] = key;
        np += (key == 0u) ? 1u : 0u;
    }
#pragma unroll
    for (int off = 32; off > 0; off >>= 1) np += __shfl_xor(np, off, 64);
    if (lane == 0) ured[wid] = np;
    __syncthreads();
    unsigned num_pos = 0;
#pragma unroll
    for (int w = 0; w < 16; ++w) num_pos += ured[w];
    const int k = (int)num_pos * NEGPOS;

    unsigned Kstar = 0xFFFFFFFFu;
    int r_eq = 0;
    bool take_all = false;
    if (k > 0) {
        unsigned prefix = 0;
        int r = k, flag = 0;
        unsigned* hist_flat = &hist[0][0];
        for (int level = 3; level >= 0; --level) {
            const int shift = level * 8;
            for (int i = tid; i < 16 * 257; i += 1024) hist_flat[i] = 0;
            __syncthreads();
            for (int j = tid; j < PRI; j += 1024) {
                const unsigned key = keys_s[j];
                if (key == 0u) continue;
                if (level < 3 && (key >> (shift + 8)) != (prefix >> (shift + 8))) continue;
                atomicAdd(&hist[wid][(key >> shift) & 255u], 1u);
            }
            __syncthreads();
            if (wid == 0) {
                const int b0 = lane * 4;
                unsigned h0 = 0, h1 = 0, h2 = 0, h3 = 0;
#pragma unroll
                for (int w = 0; w < 16; ++w) {
                    h0 += hist[w][b0]; h1 += hist[w][b0 + 1];
                    h2 += hist[w][b0 + 2]; h3 += hist[w][b0 + 3];
                }
                const unsigned loc = h0 + h1 + h2 + h3;
                unsigned ssum = loc;
#pragma unroll
                for (int o2 = 1; o2 < 64; o2 <<= 1) {
                    const unsigned t2 = __shfl_down(ssum, o2, 64);
                    if (lane + o2 < 64) ssum += t2;
                }
                const unsigned above = ssum - loc;
                const unsigned cum3 = above + h3;
                const unsigned cum2 = cum3 + h2;
                const unsigned cum1 = cum2 + h1;
                const unsigned cum0 = cum1 + h0;
                const unsigned long long msk = __ballot(cum0 >= (unsigned)r);
                if (msk == 0ULL) {
                    if (lane == 0) sh_flag = 1;
                } else {
                    const int L = 63 - __clzll(msk);
                    if (lane == L) {
                        unsigned selbin, cumsel, hsel;
                        if      (cum3 >= (unsigned)r) { selbin = b0 + 3; cumsel = cum3; hsel = h3; }
                        else if (cum2 >= (unsigned)r) { selbin = b0 + 2; cumsel = cum2; hsel = h2; }
                        else if (cum1 >= (unsigned)r) { selbin = b0 + 1; cumsel = cum1; hsel = h1; }
                        else                          { selbin = b0;     cumsel = cum0; hsel = h0; }
                        sh_prefix = prefix | (selbin << shift);
                        sh_r = (unsigned)r - (cumsel - hsel);
                        sh_flag = 0;
                    }
                }
            }
            __syncthreads();
            flag = sh_flag;
            if (flag) break;
            prefix = sh_prefix;
            r = (int)sh_r;
        }
        take_all = (flag != 0);
        if (!take_all) { Kstar = prefix; r_eq = r; }
    }

    float obj = 0.0f;
    if (k > 0) {
        for (int j = tid; j < PRI; j += 1024) {
            const unsigned key = keys_s[j];
            if (key != 0u && (take_all || key > Kstar))
                obj += __uint_as_float(key ^ 0x80000000u);
        }
        if (tid == 0 && !take_all)
            obj += (float)r_eq * __uint_as_float(Kstar ^ 0x80000000u);
    }

#pragma unroll
    for (int off = 32; off > 0; off >>= 1) obj += __shfl_xor(obj, off, 64);
    __syncthreads();
    if (lane == 0) fred[wid] = obj;
    __syncthreads();
    if (tid == 0) {
        float to = 0.0f;
#pragma unroll
        for (int w = 0; w < 16; ++w) to += fred[w];
        rowobj[row] = to;
        rownp[row]  = (float)num_pos;
    }
}

// ---------------------------------------------------------------------------
// Kernel 3 (bit-identical to R6/R12): final reduction -> 2 scalars
// ---------------------------------------------------------------------------
__global__ __launch_bounds__(256) void k_final(const float* __restrict__ cepart,
                                               const float* __restrict__ slpart,
                                               const float* __restrict__ rowobj,
                                               const float* __restrict__ rownp,
                                               float* __restrict__ out) {
    const int tid = threadIdx.x;
    float ce = 0.0f, sl = 0.0f;
    for (int i = tid; i < NPERS; i += 256) { ce += cepart[i]; sl += slpart[i]; }
    float ro = 0.0f, np = 0.0f;
    if (tid < BATCH) { ro = rowobj[tid]; np = rownp[tid]; }
#pragma unroll
    for (int off = 32; off > 0; off >>= 1) {
        ce += __shfl_xor(ce, off, 64);
        sl += __shfl_xor(sl, off, 64);
        ro += __shfl_xor(ro, off, 64);
        np += __shfl_xor(np, off, 64);
    }
    __shared__ float r0[4], r1[4], r2[4], r3[4];
    const int wid = tid >> 6, lane = tid & 63;
    if (lane == 0) { r0[wid] = ce; r1[wid] = sl; r2[wid] = ro; r3[wid] = np; }
    __syncthreads();
    if (tid == 0) {
        const float tce = r0[0] + r0[1] + r0[2] + r0[3];
        const float tsl = r1[0] + r1[1] + r1[2] + r1[3];
        const float tro = r2[0] + r2[1] + r2[2] + r2[3];
        const float tnp = r3[0] + r3[1] + r3[2] + r3[3];
        const float npos = fmaxf(tnp, 1.0f);
        out[0] = (tce + tro) / npos;
        out[1] = tsl / npos;
    }
}

extern "C" void kernel_launch(void* const* d_in, const int* in_sizes, int n_in,
                              void* d_out, int out_size, void* d_ws, size_t ws_size,
                              hipStream_t stream) {
    const float* pred_loc  = (const float*)d_in[0];
    const float* pred_conf = (const float*)d_in[1];
    const float* gt_loc    = (const float*)d_in[2];
    const int*   gt_labels = (const int*)d_in[3];
    float* out = (float*)d_out;

    unsigned* keysg   = (unsigned*)d_ws;                  // NTOT u32
    float*    cepart  = (float*)(keysg + NTOT);           // NPERS f
    float*    slpart  = cepart + NPERS;                   // NPERS f
    float*    rowobj  = slpart + NPERS;                   // BATCH f
    float*    rownp   = rowobj + BATCH;                   // BATCH f

    k_lse<<<NPERS, 256, 0, stream>>>(pred_conf, gt_labels, pred_loc, gt_loc,
                                     keysg, cepart, slpart);
    k_row<<<BATCH, 1024, 0, stream>>>(keysg, rowobj, rownp);
    k_final<<<1, 256, 0, stream>>>(cepart, slpart, rowobj, rownp, out);
}